// Round 14
// baseline (295.480 us; speedup 1.0000x reference)
//
#include <hip/hip_runtime.h>
#include <stdint.h>

typedef __bf16  bf16x8 __attribute__((ext_vector_type(8)));
typedef float   f32x4  __attribute__((ext_vector_type(4)));

#define MFMA16(a, b, c) __builtin_amdgcn_mfma_f32_16x16x32_bf16((a), (b), (c), 0, 0, 0)

__device__ __forceinline__ float bf2f(unsigned short u) {
    union { unsigned u; float f; } v; v.u = ((unsigned)u) << 16; return v.f;
}
__device__ __forceinline__ unsigned short f2bf(float f) {
    union { float f; unsigned u; } v; v.f = f;
    unsigned r = v.u + 0x7fffu + ((v.u >> 16) & 1u);
    return (unsigned short)(r >> 16);
}

// B=4, T=1024, D=512, H=8, DH=64, MAX_REL=256. Inputs fp32 dict-order; OUTPUT FP32.
// R14: attn KV-tile 64->128 (half the barriers), qsum+rbias+rmax fused per-(b,h).

// ---------- 0. cast 4 weights fp32 -> bf16 (order: q,k,v,o) ----------
__global__ __launch_bounds__(256) void cast_w(const float* __restrict__ Wq,
                                              const float* __restrict__ Wk,
                                              const float* __restrict__ Wv,
                                              const float* __restrict__ Wo,
                                              unsigned short* __restrict__ Wbf) {
    int idx = blockIdx.x * 256 + threadIdx.x;      // 1024 x 256 chunks of 4
    int which = idx >> 16, off = (idx & 65535) << 2;
    const float* src = which == 0 ? Wq : which == 1 ? Wk : which == 2 ? Wv : Wo;
    f32x4 v = *(const f32x4*)(src + off);
    ushort4 r;
    r.x = f2bf(v[0]); r.y = f2bf(v[1]); r.z = f2bf(v[2]); r.w = f2bf(v[3]);
    *(ushort4*)(Wbf + (size_t)which * 262144 + off) = r;
}

// ---------- 1a. xsum partials ----------
__global__ __launch_bounds__(256) void xsum_part(const float* __restrict__ x,
                                                 float* __restrict__ part) {
    int b = blockIdx.x, chunk = blockIdx.y, k = threadIdx.x;   // (4,32) x 256
    const float* p = x + (size_t)b * 1024 * 512 + (size_t)chunk * 32 * 512;
    float s0 = 0.f, s1 = 0.f;
    for (int t = 0; t < 32; ++t) {
        s0 += p[t * 512 + k];
        s1 += p[t * 512 + k + 256];
    }
    part[(size_t)(b * 32 + chunk) * 512 + k]       = s0;
    part[(size_t)(b * 32 + chunk) * 512 + k + 256] = s1;
}

// ---------- 1b. xsum reduce ----------
__global__ __launch_bounds__(256) void xsum_reduce(const float* __restrict__ part,
                                                   float* __restrict__ xsum) {
    int idx = blockIdx.x * 256 + threadIdx.x;      // 8 x 256
    int b = idx >> 9, k = idx & 511;
    float s = 0.f;
    for (int c = 0; c < 32; ++c) s += part[(size_t)(b * 32 + c) * 512 + k];
    xsum[idx] = s;
}

// ---------- 2. FUSED bias: per (b,h) block computes Qsum slice, R row, window-max M ----------
__global__ __launch_bounds__(256) void bias_fused(const float* __restrict__ xsum,
                                                  const float* __restrict__ Wq,
                                                  const float* __restrict__ bq,
                                                  const float* __restrict__ relT,
                                                  float* __restrict__ R,
                                                  float* __restrict__ M) {
    const int bh = blockIdx.x;                     // 32 blocks
    const int b = bh >> 3, h = bh & 7;
    __shared__ float qs[64];
    __shared__ float L[2][513];
    __shared__ float L8[513];
    int tid = threadIdx.x, wave = tid >> 6, lane = tid & 63;

    // Qsum[b][h*64+j] for j=0..63 (wave per j, 16 each)
    const float* xs = xsum + b * 512;
    for (int j = wave; j < 64; j += 4) {
        int n = h * 64 + j;
        const float* w = Wq + (size_t)n * 512;
        float s = 0.f;
        for (int kk = lane; kk < 512; kk += 64) s += xs[kk] * w[kk];
        for (int off = 32; off; off >>= 1) s += __shfl_xor(s, off, 64);
        if (lane == 0) qs[j] = s + 1024.0f * bq[n];
    }
    __syncthreads();

    // R[delta] = 0.125 * qs . relT[delta]
    for (int dlt = wave; dlt < 513; dlt += 4) {
        float s = qs[lane] * relT[(size_t)dlt * 64 + lane];
        for (int off = 32; off; off >>= 1) s += __shfl_xor(s, off, 64);
        if (lane == 0) {
            float r = 0.125f * s;
            L[0][dlt] = r;
            R[bh * 513 + dlt] = r;
        }
    }
    __syncthreads();

    // sparse-table window max (levels up to 9; keep level 8)
    int cur = 0;
    for (int k = 1; k <= 9; ++k) {
        int half = 1 << (k - 1), nxt = cur ^ 1;
        for (int i = tid; i < 513; i += 256) {
            int j = i + half; if (j > 512) j = 512;
            L[nxt][i] = fmaxf(L[cur][i], L[cur][j]);
        }
        __syncthreads();
        if (k == 8) {
            for (int i = tid; i < 513; i += 256) L8[i] = L[nxt][i];
            __syncthreads();
        }
        cur = nxt;
    }
    for (int t = tid; t < 1024; t += 256) {
        int lo = 256 - (t < 256 ? t : 256);
        int hi = 256 + ((1023 - t) < 256 ? (1023 - t) : 256);
        int len = hi - lo + 1;
        float m = (len >= 512) ? fmaxf(L[cur][lo], L[cur][hi - 511])
                               : fmaxf(L8[lo], L8[hi - 255]);
        M[bh * 1024 + t] = m;
    }
}

// ---------- fp32 64x64 tile (ld=512) -> bf16 LDS [64][72] ----------
__device__ __forceinline__ void stage_f32(const float* __restrict__ src, int row0, int k0,
                                          unsigned short (*dst)[72], int tid) {
    for (int c = tid; c < 1024; c += 256) {
        int row = c >> 4, kc = (c & 15) << 2;
        f32x4 v = *(const f32x4*)(src + (size_t)(row0 + row) * 512 + k0 + kc);
        ushort4 r;
        r.x = f2bf(v[0]); r.y = f2bf(v[1]); r.z = f2bf(v[2]); r.w = f2bf(v[3]);
        *(ushort4*)(&dst[row][kc]) = r;
    }
}

// ---------- 3. FUSED QKV projection (MFMA). Q,K -> (B,H,T,DH); V -> (B,H,DH,T) ----------
__global__ __launch_bounds__(256) void qkv_fused(
    const float* __restrict__ x, const unsigned short* __restrict__ Wbf,
    const float* __restrict__ bq, const float* __restrict__ bk, const float* __restrict__ bv,
    unsigned short* __restrict__ Qb, unsigned short* __restrict__ Kb,
    unsigned short* __restrict__ VbT) {
    const int m0 = blockIdx.y * 64;
    const int n0 = blockIdx.x * 64;

    __shared__ __align__(16) unsigned short As[64][72];
    __shared__ __align__(16) unsigned short Ws3[3][64][72];

    int tid = threadIdx.x;
    int wave = tid >> 6, lane = tid & 63, quad = lane >> 4, l16 = lane & 15;
    int arow = wave * 16 + l16;

    f32x4 acc[3][4] = {};

    for (int k0 = 0; k0 < 512; k0 += 64) {
        stage_f32(x, m0, k0, As, tid);
        for (int w = 0; w < 3; ++w) {
            const unsigned short* Wp = Wbf + (size_t)w * 262144;
            for (int c = tid; c < 512; c += 256) {
                int row = c >> 3, kc = (c & 7) << 3;
                *(uint4*)(&Ws3[w][row][kc]) =
                    *(const uint4*)(Wp + (size_t)(n0 + row) * 512 + k0 + kc);
            }
        }
        __syncthreads();
        for (int kk = 0; kk < 2; ++kk) {
            bf16x8 af = *(const bf16x8*)(&As[arow][kk * 32 + quad * 8]);
            for (int w = 0; w < 3; ++w) {
                for (int nt = 0; nt < 4; ++nt) {
                    bf16x8 bfv = *(const bf16x8*)(&Ws3[w][nt * 16 + l16][kk * 32 + quad * 8]);
                    acc[w][nt] = MFMA16(af, bfv, acc[w][nt]);
                }
            }
        }
        __syncthreads();
    }

    for (int w = 0; w < 2; ++w) {
        unsigned short* Out = (w == 0) ? Qb : Kb;
        const float* bias = (w == 0) ? bq : bk;
        for (int nt = 0; nt < 4; ++nt) {
            int col = n0 + nt * 16 + l16;
            int h = col >> 6, d = col & 63;
            float bv_ = bias[col];
            for (int reg = 0; reg < 4; ++reg) {
                int row = m0 + wave * 16 + quad * 4 + reg;     // = b*1024 + t
                int b = row >> 10, t = row & 1023;
                Out[(((size_t)(b * 8 + h) * 1024 + t) << 6) + d] = f2bf(acc[w][nt][reg] + bv_);
            }
        }
    }
    __syncthreads();
    for (int nt = 0; nt < 4; ++nt) {
        int dl = nt * 16 + l16;
        float bv_ = bv[n0 + dl];
        for (int reg = 0; reg < 4; ++reg)
            As[dl][wave * 16 + quad * 4 + reg] = f2bf(acc[2][nt][reg] + bv_);
    }
    __syncthreads();
    const int h = n0 >> 6, b = m0 >> 10, tg = m0 & 1023;
    for (int c = tid; c < 512; c += 256) {
        int dl = c >> 3, seg = (c & 7) << 3;
        *(uint4*)(VbT + (((size_t)((b * 8 + h) * 64 + dl)) << 10) + tg + seg) =
            *(const uint4*)(&As[dl][seg]);
    }
}

// ---------- 4. MFMA flash attention, KV-tile=128, static row-max, reg prefetch ----------
__global__ __launch_bounds__(256) void attn_kernel(
    unsigned short* __restrict__ Qb,
    const unsigned short* __restrict__ Kb, const unsigned short* __restrict__ VbT,
    const float* __restrict__ R, const float* __restrict__ M) {
    const int bh = blockIdx.y;
    const int t0 = blockIdx.x * 64;
    __shared__ __align__(16) unsigned short Ks[128][72];   // K[s][dh]
    __shared__ __align__(16) unsigned short Vt[64][136];   // V^T[dh][s]
    __shared__ __align__(16) unsigned short Ps[64][136];   // P[t][s]
    __shared__ float Rs[513];

    int tid = threadIdx.x, wave = tid >> 6, lane = tid & 63, quad = lane >> 4, l16 = lane & 15;

    for (int i = tid; i < 513; i += 256) Rs[i] = R[bh * 513 + i];

    unsigned short* Qp = Qb + ((size_t)bh * 1024 + t0) * 64;
    int arow = wave * 16 + l16;
    bf16x8 qf0 = *(const bf16x8*)(Qp + arow * 64 + quad * 8);
    bf16x8 qf1 = *(const bf16x8*)(Qp + arow * 64 + 32 + quad * 8);

    float mrow[4];
    for (int reg = 0; reg < 4; ++reg)
        mrow[reg] = M[bh * 1024 + t0 + wave * 16 + quad * 4 + reg];

    const unsigned short* Kp  = Kb  + (size_t)bh * 65536;
    const unsigned short* Vtp = VbT + (size_t)bh * 65536;

    // K: 1024 uint4 chunks (row 0..127, kc 0..56); V: 1024 uint4 (dh 0..63, seg 0..120)
    int kr[4], kc[4], vd[4], vs[4];
    uint4 kreg[4], vreg[4];
    for (int i = 0; i < 4; ++i) {
        int c = tid + i * 256;
        kr[i] = c >> 3;  kc[i] = (c & 7) << 3;
        vd[i] = c >> 4;  vs[i] = (c & 15) << 3;
        kreg[i] = *(const uint4*)(Kp + (size_t)kr[i] * 64 + kc[i]);
        vreg[i] = *(const uint4*)(Vtp + ((size_t)vd[i] << 10) + vs[i]);
    }

    f32x4 acco[4] = {};
    float lsum[4] = {0.f, 0.f, 0.f, 0.f};

    for (int s0 = 0; s0 < 1024; s0 += 128) {
        __syncthreads();   // consumers of previous tile done
        for (int i = 0; i < 4; ++i) {
            *(uint4*)(&Ks[kr[i]][kc[i]]) = kreg[i];
            *(uint4*)(&Vt[vd[i]][vs[i]]) = vreg[i];
        }
        int sn = s0 + 128;
        if (sn < 1024) {
            for (int i = 0; i < 4; ++i) {
                kreg[i] = *(const uint4*)(Kp + (size_t)(sn + kr[i]) * 64 + kc[i]);
                vreg[i] = *(const uint4*)(Vtp + ((size_t)vd[i] << 10) + sn + vs[i]);
            }
        }
        __syncthreads();   // staging visible

        // S = Q K^T (64 x 128)
        f32x4 accs[8] = {};
        for (int nt = 0; nt < 8; ++nt) {
            bf16x8 kf0 = *(const bf16x8*)(&Ks[nt * 16 + l16][quad * 8]);
            accs[nt] = MFMA16(qf0, kf0, accs[nt]);
            bf16x8 kf1 = *(const bf16x8*)(&Ks[nt * 16 + l16][32 + quad * 8]);
            accs[nt] = MFMA16(qf1, kf1, accs[nt]);
        }

        // static-max softmax; per-lane l accumulation
        for (int reg = 0; reg < 4; ++reg) {
            int tt = t0 + wave * 16 + quad * 4 + reg;
            for (int nt = 0; nt < 8; ++nt) {
                int ss = s0 + nt * 16 + l16;
                int dlt = ss - tt;
                dlt = dlt > 256 ? 256 : (dlt < -256 ? -256 : dlt);
                float v = accs[nt][reg] * 0.125f + Rs[dlt + 256];
                float p = __expf(v - mrow[reg]);
                lsum[reg] += p;
                Ps[wave * 16 + quad * 4 + reg][nt * 16 + l16] = f2bf(p);
            }
        }
        // Ps rows wave-private: program order suffices before PV

        for (int kk = 0; kk < 4; ++kk) {
            bf16x8 pf = *(const bf16x8*)(&Ps[wave * 16 + l16][kk * 32 + quad * 8]);
            for (int nt = 0; nt < 4; ++nt) {
                bf16x8 vf = *(const bf16x8*)(&Vt[nt * 16 + l16][kk * 32 + quad * 8]);
                acco[nt] = MFMA16(pf, vf, acco[nt]);
            }
        }
    }

    for (int reg = 0; reg < 4; ++reg)
        for (int off = 1; off < 16; off <<= 1) lsum[reg] += __shfl_xor(lsum[reg], off, 64);

    for (int nt = 0; nt < 4; ++nt) {
        for (int reg = 0; reg < 4; ++reg) {
            int tt = t0 + wave * 16 + quad * 4 + reg;
            int d = nt * 16 + l16;
            Qb[((size_t)bh * 1024 + tt) * 64 + d] = f2bf(acco[nt][reg] / lsum[reg]);
        }
    }
}

// ---------- 5. output projection (MFMA, bf16 Wo): out = AO @ Wo^T + bo, fp32 ----------
__global__ __launch_bounds__(256) void out_proj(
    const unsigned short* __restrict__ AObf, const unsigned short* __restrict__ Wobf,
    const float* __restrict__ bo, float* __restrict__ out) {
    const int m0 = blockIdx.y * 64;
    const int n0 = blockIdx.x * 64;
    const int b = m0 >> 10, tt0 = m0 & 1023;
    __shared__ __align__(16) unsigned short As[64][72];
    __shared__ __align__(16) unsigned short Bs[64][72];
    int tid = threadIdx.x, wave = tid >> 6, lane = tid & 63, quad = lane >> 4, l16 = lane & 15;
    int arow = wave * 16 + l16;
    f32x4 acc[4] = {};
    for (int k0 = 0; k0 < 512; k0 += 64) {
        const int h = k0 >> 6;
        for (int c = tid; c < 512; c += 256) {
            int row = c >> 3, kc = (c & 7) << 3;
            *(uint4*)(&As[row][kc]) =
                *(const uint4*)(AObf + (((size_t)(b * 8 + h) * 1024 + tt0 + row) << 6) + kc);
            *(uint4*)(&Bs[row][kc]) =
                *(const uint4*)(Wobf + (size_t)(n0 + row) * 512 + k0 + kc);
        }
        __syncthreads();
        for (int kk = 0; kk < 2; ++kk) {
            bf16x8 af = *(const bf16x8*)(&As[arow][kk * 32 + quad * 8]);
            for (int nt = 0; nt < 4; ++nt) {
                bf16x8 bfv = *(const bf16x8*)(&Bs[nt * 16 + l16][kk * 32 + quad * 8]);
                acc[nt] = MFMA16(af, bfv, acc[nt]);
            }
        }
        __syncthreads();
    }
    for (int nt = 0; nt < 4; ++nt) {
        int col = n0 + nt * 16 + l16;
        float bv_ = bo[col];
        for (int reg = 0; reg < 4; ++reg) {
            int row = m0 + wave * 16 + quad * 4 + reg;
            out[(size_t)row * 512 + col] = acc[nt][reg] + bv_;
        }
    }
}

extern "C" void kernel_launch(void* const* d_in, const int* in_sizes, int n_in,
                              void* d_out, int out_size, void* d_ws, size_t ws_size,
                              hipStream_t stream) {
    const void* x = nullptr; const void* Ws[4] = {}; const void* bs[4] = {};
    const void* relT = nullptr;
    int wi = 0, bi = 0, idx_x = -1;
    for (int i = 0; i < n_in; ++i) {
        long s = in_sizes[i];
        if ((s == 2097152 || s == 8388608) && !x) { x = d_in[i]; idx_x = i; }
        else if ((s == 262144 || s == 1048576) && wi < 4) Ws[wi++] = d_in[i];
        else if ((s == 512 || s == 2048) && bi < 4) bs[bi++] = d_in[i];
        else if ((s == 32832 || s == 131328) && !relT) relT = d_in[i];
    }
    const float *Wq, *Wk, *Wv, *Wo, *bq, *bk, *bv, *bo;
    if (x && wi == 4 && bi == 4 && relT) {
        bool sorted_order = (idx_x != 0);    // measured: dict order (idx_x==0)
        if (sorted_order) {
            Wq = (const float*)Ws[2]; Wk = (const float*)Ws[0];
            Wv = (const float*)Ws[3]; Wo = (const float*)Ws[1];
            bq = (const float*)bs[2]; bk = (const float*)bs[0];
            bv = (const float*)bs[3]; bo = (const float*)bs[1];
        } else {
            Wq = (const float*)Ws[0]; Wk = (const float*)Ws[1];
            Wv = (const float*)Ws[2]; Wo = (const float*)Ws[3];
            bq = (const float*)bs[0]; bk = (const float*)bs[1];
            bv = (const float*)bs[2]; bo = (const float*)bs[3];
        }
    } else {
        x = d_in[0];
        Wq = (const float*)d_in[2]; bq = (const float*)d_in[3];
        Wk = (const float*)d_in[4]; bk = (const float*)d_in[5];
        Wv = (const float*)d_in[6]; bv = (const float*)d_in[7];
        Wo = (const float*)d_in[8]; bo = (const float*)d_in[9];
        relT = d_in[10];
    }
    const float* xf  = (const float*)x;
    const float* rel = (const float*)relT;
    float* out = (float*)d_out;

    // ws: hdr 128K | Qb/Kb/VbT 3x4M | part 256K | M 128K | Wbf 2M  = 14.5 MiB
    char* ws = (char*)d_ws;
    float* xsum = (float*)(ws);
    float* Rbuf = (float*)(ws + 16384);
    unsigned short* Qb  = (unsigned short*)(ws + 131072);
    unsigned short* Kb  = (unsigned short*)(ws + 131072 + (4 << 20));
    unsigned short* VbT = (unsigned short*)(ws + 131072 + (8 << 20));
    char* tail = ws + 131072 + (12 << 20);
    float* part = (float*)(tail);                        // 256 KB
    float* Mbuf = (float*)(tail + 262144);               // 128 KB
    unsigned short* Wbf = (unsigned short*)(tail + 262144 + 131072);   // 2 MiB (q,k,v,o)

    cast_w<<<dim3(1024), dim3(256), 0, stream>>>(Wq, Wk, Wv, Wo, Wbf);
    xsum_part<<<dim3(4, 32), dim3(256), 0, stream>>>(xf, part);
    xsum_reduce<<<dim3(8), dim3(256), 0, stream>>>(part, xsum);
    bias_fused<<<dim3(32), dim3(256), 0, stream>>>(xsum, Wq, bq, rel, Rbuf, Mbuf);
    qkv_fused<<<dim3(8, 64), dim3(256), 0, stream>>>(xf, Wbf, bq, bk, bv, Qb, Kb, VbT);
    attn_kernel<<<dim3(16, 32), dim3(256), 0, stream>>>(Qb, Kb, VbT, Rbuf, Mbuf);
    out_proj<<<dim3(8, 64), dim3(256), 0, stream>>>(Qb, Wbf + 3 * 262144, bo, out);
}

// Round 15
// 198.089 us; speedup vs baseline: 1.4916x; 1.4916x over previous
//
#include <hip/hip_runtime.h>
#include <stdint.h>

typedef __bf16  bf16x8 __attribute__((ext_vector_type(8)));
typedef float   f32x4  __attribute__((ext_vector_type(4)));

#define MFMA16(a, b, c) __builtin_amdgcn_mfma_f32_16x16x32_bf16((a), (b), (c), 0, 0, 0)

__device__ __forceinline__ float bf2f(unsigned short u) {
    union { unsigned u; float f; } v; v.u = ((unsigned)u) << 16; return v.f;
}
__device__ __forceinline__ unsigned short f2bf(float f) {
    union { float f; unsigned u; } v; v.f = f;
    unsigned r = v.u + 0x7fffu + ((v.u >> 16) & 1u);
    return (unsigned short)(r >> 16);
}

// B=4, T=1024, D=512, H=8, DH=64, MAX_REL=256. Inputs fp32 dict-order; OUTPUT FP32.
// R15: revert bias path to R13's parallel kernels (bias_fused was -95us: 32 blocks
// of serialized latency). Keep attn KV-tile=128 to measure it in isolation.

// ---------- 0. cast 4 weights fp32 -> bf16 (order: q,k,v,o) ----------
__global__ __launch_bounds__(256) void cast_w(const float* __restrict__ Wq,
                                              const float* __restrict__ Wk,
                                              const float* __restrict__ Wv,
                                              const float* __restrict__ Wo,
                                              unsigned short* __restrict__ Wbf) {
    int idx = blockIdx.x * 256 + threadIdx.x;      // 1024 x 256 chunks of 4
    int which = idx >> 16, off = (idx & 65535) << 2;
    const float* src = which == 0 ? Wq : which == 1 ? Wk : which == 2 ? Wv : Wo;
    f32x4 v = *(const f32x4*)(src + off);
    ushort4 r;
    r.x = f2bf(v[0]); r.y = f2bf(v[1]); r.z = f2bf(v[2]); r.w = f2bf(v[3]);
    *(ushort4*)(Wbf + (size_t)which * 262144 + off) = r;
}

// ---------- 1a. xsum partials ----------
__global__ __launch_bounds__(256) void xsum_part(const float* __restrict__ x,
                                                 float* __restrict__ part) {
    int b = blockIdx.x, chunk = blockIdx.y, k = threadIdx.x;   // (4,32) x 256
    const float* p = x + (size_t)b * 1024 * 512 + (size_t)chunk * 32 * 512;
    float s0 = 0.f, s1 = 0.f;
    for (int t = 0; t < 32; ++t) {
        s0 += p[t * 512 + k];
        s1 += p[t * 512 + k + 256];
    }
    part[(size_t)(b * 32 + chunk) * 512 + k]       = s0;
    part[(size_t)(b * 32 + chunk) * 512 + k + 256] = s1;
}

// ---------- 1b. xsum reduce ----------
__global__ __launch_bounds__(256) void xsum_reduce(const float* __restrict__ part,
                                                   float* __restrict__ xsum) {
    int idx = blockIdx.x * 256 + threadIdx.x;      // 8 x 256
    int b = idx >> 9, k = idx & 511;
    float s = 0.f;
    for (int c = 0; c < 32; ++c) s += part[(size_t)(b * 32 + c) * 512 + k];
    xsum[idx] = s;
}

// ---------- 2. Qsum (wave per output; 512 blocks) ----------
__global__ __launch_bounds__(256) void qsum_kernel(const float* __restrict__ xsum,
                                                   const float* __restrict__ Wq,
                                                   const float* __restrict__ bq,
                                                   float* __restrict__ Qsum) {
    int idx = blockIdx.x * 4 + (threadIdx.x >> 6);
    int lane = threadIdx.x & 63;
    int b = idx >> 9, n = idx & 511;
    const float* xs = xsum + b * 512;
    const float* w = Wq + (size_t)n * 512;
    float s = 0.f;
    for (int j = lane; j < 512; j += 64) s += xs[j] * w[j];
    for (int off = 32; off; off >>= 1) s += __shfl_xor(s, off, 64);
    if (lane == 0) Qsum[idx] = s + 1024.0f * bq[n];
}

// ---------- 3. R bias (wave per output; 4104 blocks) ----------
__global__ __launch_bounds__(256) void rbias_kernel(const float* __restrict__ Qsum,
                                                    const float* __restrict__ relT,
                                                    float* __restrict__ R) {
    int idx = blockIdx.x * 4 + (threadIdx.x >> 6);
    if (idx >= 4 * 8 * 513) return;
    int lane = threadIdx.x & 63;
    int delta = idx % 513, bh = idx / 513;
    int b = bh >> 3, h = bh & 7;
    float s = Qsum[b * 512 + h * 64 + lane] * relT[(size_t)delta * 64 + lane];
    for (int off = 32; off; off >>= 1) s += __shfl_xor(s, off, 64);
    if (lane == 0) R[idx] = 0.125f * s;
}

// ---------- 3b. M[bh][t] = exact max of R over clipped delta window ----------
__global__ __launch_bounds__(256) void rmax_kernel(const float* __restrict__ R,
                                                   float* __restrict__ M) {
    __shared__ float L[2][513];
    __shared__ float L8[513];
    int bh = blockIdx.x, tid = threadIdx.x;
    for (int i = tid; i < 513; i += 256) L[0][i] = R[bh * 513 + i];
    __syncthreads();
    int cur = 0;
    for (int k = 1; k <= 9; ++k) {
        int half = 1 << (k - 1), nxt = cur ^ 1;
        for (int i = tid; i < 513; i += 256) {
            int j = i + half; if (j > 512) j = 512;
            L[nxt][i] = fmaxf(L[cur][i], L[cur][j]);
        }
        __syncthreads();
        if (k == 8) {
            for (int i = tid; i < 513; i += 256) L8[i] = L[nxt][i];
            __syncthreads();
        }
        cur = nxt;
    }
    for (int t = tid; t < 1024; t += 256) {
        int lo = 256 - (t < 256 ? t : 256);
        int hi = 256 + ((1023 - t) < 256 ? (1023 - t) : 256);
        int len = hi - lo + 1;
        float m = (len >= 512) ? fmaxf(L[cur][lo], L[cur][hi - 511])
                               : fmaxf(L8[lo], L8[hi - 255]);
        M[bh * 1024 + t] = m;
    }
}

// ---------- fp32 64x64 tile (ld=512) -> bf16 LDS [64][72] ----------
__device__ __forceinline__ void stage_f32(const float* __restrict__ src, int row0, int k0,
                                          unsigned short (*dst)[72], int tid) {
    for (int c = tid; c < 1024; c += 256) {
        int row = c >> 4, kc = (c & 15) << 2;
        f32x4 v = *(const f32x4*)(src + (size_t)(row0 + row) * 512 + k0 + kc);
        ushort4 r;
        r.x = f2bf(v[0]); r.y = f2bf(v[1]); r.z = f2bf(v[2]); r.w = f2bf(v[3]);
        *(ushort4*)(&dst[row][kc]) = r;
    }
}

// ---------- 4. FUSED QKV projection (MFMA). Q,K -> (B,H,T,DH); V -> (B,H,DH,T) ----------
__global__ __launch_bounds__(256) void qkv_fused(
    const float* __restrict__ x, const unsigned short* __restrict__ Wbf,
    const float* __restrict__ bq, const float* __restrict__ bk, const float* __restrict__ bv,
    unsigned short* __restrict__ Qb, unsigned short* __restrict__ Kb,
    unsigned short* __restrict__ VbT) {
    const int m0 = blockIdx.y * 64;
    const int n0 = blockIdx.x * 64;

    __shared__ __align__(16) unsigned short As[64][72];
    __shared__ __align__(16) unsigned short Ws3[3][64][72];

    int tid = threadIdx.x;
    int wave = tid >> 6, lane = tid & 63, quad = lane >> 4, l16 = lane & 15;
    int arow = wave * 16 + l16;

    f32x4 acc[3][4] = {};

    for (int k0 = 0; k0 < 512; k0 += 64) {
        stage_f32(x, m0, k0, As, tid);
        for (int w = 0; w < 3; ++w) {
            const unsigned short* Wp = Wbf + (size_t)w * 262144;
            for (int c = tid; c < 512; c += 256) {
                int row = c >> 3, kc = (c & 7) << 3;
                *(uint4*)(&Ws3[w][row][kc]) =
                    *(const uint4*)(Wp + (size_t)(n0 + row) * 512 + k0 + kc);
            }
        }
        __syncthreads();
        for (int kk = 0; kk < 2; ++kk) {
            bf16x8 af = *(const bf16x8*)(&As[arow][kk * 32 + quad * 8]);
            for (int w = 0; w < 3; ++w) {
                for (int nt = 0; nt < 4; ++nt) {
                    bf16x8 bfv = *(const bf16x8*)(&Ws3[w][nt * 16 + l16][kk * 32 + quad * 8]);
                    acc[w][nt] = MFMA16(af, bfv, acc[w][nt]);
                }
            }
        }
        __syncthreads();
    }

    for (int w = 0; w < 2; ++w) {
        unsigned short* Out = (w == 0) ? Qb : Kb;
        const float* bias = (w == 0) ? bq : bk;
        for (int nt = 0; nt < 4; ++nt) {
            int col = n0 + nt * 16 + l16;
            int h = col >> 6, d = col & 63;
            float bv_ = bias[col];
            for (int reg = 0; reg < 4; ++reg) {
                int row = m0 + wave * 16 + quad * 4 + reg;     // = b*1024 + t
                int b = row >> 10, t = row & 1023;
                Out[(((size_t)(b * 8 + h) * 1024 + t) << 6) + d] = f2bf(acc[w][nt][reg] + bv_);
            }
        }
    }
    __syncthreads();
    for (int nt = 0; nt < 4; ++nt) {
        int dl = nt * 16 + l16;
        float bv_ = bv[n0 + dl];
        for (int reg = 0; reg < 4; ++reg)
            As[dl][wave * 16 + quad * 4 + reg] = f2bf(acc[2][nt][reg] + bv_);
    }
    __syncthreads();
    const int h = n0 >> 6, b = m0 >> 10, tg = m0 & 1023;
    for (int c = tid; c < 512; c += 256) {
        int dl = c >> 3, seg = (c & 7) << 3;
        *(uint4*)(VbT + (((size_t)((b * 8 + h) * 64 + dl)) << 10) + tg + seg) =
            *(const uint4*)(&As[dl][seg]);
    }
}

// ---------- 5. MFMA flash attention, KV-tile=128, static row-max, reg prefetch ----------
__global__ __launch_bounds__(256) void attn_kernel(
    unsigned short* __restrict__ Qb,
    const unsigned short* __restrict__ Kb, const unsigned short* __restrict__ VbT,
    const float* __restrict__ R, const float* __restrict__ M) {
    const int bh = blockIdx.y;
    const int t0 = blockIdx.x * 64;
    __shared__ __align__(16) unsigned short Ks[128][72];   // K[s][dh]
    __shared__ __align__(16) unsigned short Vt[64][136];   // V^T[dh][s]
    __shared__ __align__(16) unsigned short Ps[64][136];   // P[t][s]
    __shared__ float Rs[513];

    int tid = threadIdx.x, wave = tid >> 6, lane = tid & 63, quad = lane >> 4, l16 = lane & 15;

    for (int i = tid; i < 513; i += 256) Rs[i] = R[bh * 513 + i];

    unsigned short* Qp = Qb + ((size_t)bh * 1024 + t0) * 64;
    int arow = wave * 16 + l16;
    bf16x8 qf0 = *(const bf16x8*)(Qp + arow * 64 + quad * 8);
    bf16x8 qf1 = *(const bf16x8*)(Qp + arow * 64 + 32 + quad * 8);

    float mrow[4];
    for (int reg = 0; reg < 4; ++reg)
        mrow[reg] = M[bh * 1024 + t0 + wave * 16 + quad * 4 + reg];

    const unsigned short* Kp  = Kb  + (size_t)bh * 65536;
    const unsigned short* Vtp = VbT + (size_t)bh * 65536;

    int kr[4], kc[4], vd[4], vs[4];
    uint4 kreg[4], vreg[4];
    for (int i = 0; i < 4; ++i) {
        int c = tid + i * 256;
        kr[i] = c >> 3;  kc[i] = (c & 7) << 3;
        vd[i] = c >> 4;  vs[i] = (c & 15) << 3;
        kreg[i] = *(const uint4*)(Kp + (size_t)kr[i] * 64 + kc[i]);
        vreg[i] = *(const uint4*)(Vtp + ((size_t)vd[i] << 10) + vs[i]);
    }

    f32x4 acco[4] = {};
    float lsum[4] = {0.f, 0.f, 0.f, 0.f};

    for (int s0 = 0; s0 < 1024; s0 += 128) {
        __syncthreads();
        for (int i = 0; i < 4; ++i) {
            *(uint4*)(&Ks[kr[i]][kc[i]]) = kreg[i];
            *(uint4*)(&Vt[vd[i]][vs[i]]) = vreg[i];
        }
        int sn = s0 + 128;
        if (sn < 1024) {
            for (int i = 0; i < 4; ++i) {
                kreg[i] = *(const uint4*)(Kp + (size_t)(sn + kr[i]) * 64 + kc[i]);
                vreg[i] = *(const uint4*)(Vtp + ((size_t)vd[i] << 10) + sn + vs[i]);
            }
        }
        __syncthreads();

        f32x4 accs[8] = {};
        for (int nt = 0; nt < 8; ++nt) {
            bf16x8 kf0 = *(const bf16x8*)(&Ks[nt * 16 + l16][quad * 8]);
            accs[nt] = MFMA16(qf0, kf0, accs[nt]);
            bf16x8 kf1 = *(const bf16x8*)(&Ks[nt * 16 + l16][32 + quad * 8]);
            accs[nt] = MFMA16(qf1, kf1, accs[nt]);
        }

        for (int reg = 0; reg < 4; ++reg) {
            int tt = t0 + wave * 16 + quad * 4 + reg;
            for (int nt = 0; nt < 8; ++nt) {
                int ss = s0 + nt * 16 + l16;
                int dlt = ss - tt;
                dlt = dlt > 256 ? 256 : (dlt < -256 ? -256 : dlt);
                float v = accs[nt][reg] * 0.125f + Rs[dlt + 256];
                float p = __expf(v - mrow[reg]);
                lsum[reg] += p;
                Ps[wave * 16 + quad * 4 + reg][nt * 16 + l16] = f2bf(p);
            }
        }

        for (int kk = 0; kk < 4; ++kk) {
            bf16x8 pf = *(const bf16x8*)(&Ps[wave * 16 + l16][kk * 32 + quad * 8]);
            for (int nt = 0; nt < 4; ++nt) {
                bf16x8 vf = *(const bf16x8*)(&Vt[nt * 16 + l16][kk * 32 + quad * 8]);
                acco[nt] = MFMA16(pf, vf, acco[nt]);
            }
        }
    }

    for (int reg = 0; reg < 4; ++reg)
        for (int off = 1; off < 16; off <<= 1) lsum[reg] += __shfl_xor(lsum[reg], off, 64);

    for (int nt = 0; nt < 4; ++nt) {
        for (int reg = 0; reg < 4; ++reg) {
            int tt = t0 + wave * 16 + quad * 4 + reg;
            int d = nt * 16 + l16;
            Qb[((size_t)bh * 1024 + tt) * 64 + d] = f2bf(acco[nt][reg] / lsum[reg]);
        }
    }
}

// ---------- 6. output projection (MFMA, bf16 Wo): out = AO @ Wo^T + bo, fp32 ----------
__global__ __launch_bounds__(256) void out_proj(
    const unsigned short* __restrict__ AObf, const unsigned short* __restrict__ Wobf,
    const float* __restrict__ bo, float* __restrict__ out) {
    const int m0 = blockIdx.y * 64;
    const int n0 = blockIdx.x * 64;
    const int b = m0 >> 10, tt0 = m0 & 1023;
    __shared__ __align__(16) unsigned short As[64][72];
    __shared__ __align__(16) unsigned short Bs[64][72];
    int tid = threadIdx.x, wave = tid >> 6, lane = tid & 63, quad = lane >> 4, l16 = lane & 15;
    int arow = wave * 16 + l16;
    f32x4 acc[4] = {};
    for (int k0 = 0; k0 < 512; k0 += 64) {
        const int h = k0 >> 6;
        for (int c = tid; c < 512; c += 256) {
            int row = c >> 3, kc = (c & 7) << 3;
            *(uint4*)(&As[row][kc]) =
                *(const uint4*)(AObf + (((size_t)(b * 8 + h) * 1024 + tt0 + row) << 6) + kc);
            *(uint4*)(&Bs[row][kc]) =
                *(const uint4*)(Wobf + (size_t)(n0 + row) * 512 + k0 + kc);
        }
        __syncthreads();
        for (int kk = 0; kk < 2; ++kk) {
            bf16x8 af = *(const bf16x8*)(&As[arow][kk * 32 + quad * 8]);
            for (int nt = 0; nt < 4; ++nt) {
                bf16x8 bfv = *(const bf16x8*)(&Bs[nt * 16 + l16][kk * 32 + quad * 8]);
                acc[nt] = MFMA16(af, bfv, acc[nt]);
            }
        }
        __syncthreads();
    }
    for (int nt = 0; nt < 4; ++nt) {
        int col = n0 + nt * 16 + l16;
        float bv_ = bo[col];
        for (int reg = 0; reg < 4; ++reg) {
            int row = m0 + wave * 16 + quad * 4 + reg;
            out[(size_t)row * 512 + col] = acc[nt][reg] + bv_;
        }
    }
}

extern "C" void kernel_launch(void* const* d_in, const int* in_sizes, int n_in,
                              void* d_out, int out_size, void* d_ws, size_t ws_size,
                              hipStream_t stream) {
    const void* x = nullptr; const void* Ws[4] = {}; const void* bs[4] = {};
    const void* relT = nullptr;
    int wi = 0, bi = 0, idx_x = -1;
    for (int i = 0; i < n_in; ++i) {
        long s = in_sizes[i];
        if ((s == 2097152 || s == 8388608) && !x) { x = d_in[i]; idx_x = i; }
        else if ((s == 262144 || s == 1048576) && wi < 4) Ws[wi++] = d_in[i];
        else if ((s == 512 || s == 2048) && bi < 4) bs[bi++] = d_in[i];
        else if ((s == 32832 || s == 131328) && !relT) relT = d_in[i];
    }
    const float *Wq, *Wk, *Wv, *Wo, *bq, *bk, *bv, *bo;
    if (x && wi == 4 && bi == 4 && relT) {
        bool sorted_order = (idx_x != 0);    // measured: dict order (idx_x==0)
        if (sorted_order) {
            Wq = (const float*)Ws[2]; Wk = (const float*)Ws[0];
            Wv = (const float*)Ws[3]; Wo = (const float*)Ws[1];
            bq = (const float*)bs[2]; bk = (const float*)bs[0];
            bv = (const float*)bs[3]; bo = (const float*)bs[1];
        } else {
            Wq = (const float*)Ws[0]; Wk = (const float*)Ws[1];
            Wv = (const float*)Ws[2]; Wo = (const float*)Ws[3];
            bq = (const float*)bs[0]; bk = (const float*)bs[1];
            bv = (const float*)bs[2]; bo = (const float*)bs[3];
        }
    } else {
        x = d_in[0];
        Wq = (const float*)d_in[2]; bq = (const float*)d_in[3];
        Wk = (const float*)d_in[4]; bk = (const float*)d_in[5];
        Wv = (const float*)d_in[6]; bv = (const float*)d_in[7];
        Wo = (const float*)d_in[8]; bo = (const float*)d_in[9];
        relT = d_in[10];
    }
    const float* xf  = (const float*)x;
    const float* rel = (const float*)relT;
    float* out = (float*)d_out;

    // ws: hdr 128K | Qb/Kb/VbT 3x4M | part 256K | M 128K | Wbf 2M  = 14.5 MiB
    char* ws = (char*)d_ws;
    float* xsum = (float*)(ws);
    float* Qsum = (float*)(ws + 8192);
    float* Rbuf = (float*)(ws + 16384);
    unsigned short* Qb  = (unsigned short*)(ws + 131072);
    unsigned short* Kb  = (unsigned short*)(ws + 131072 + (4 << 20));
    unsigned short* VbT = (unsigned short*)(ws + 131072 + (8 << 20));
    char* tail = ws + 131072 + (12 << 20);
    float* part = (float*)(tail);                        // 256 KB
    float* Mbuf = (float*)(tail + 262144);               // 128 KB
    unsigned short* Wbf = (unsigned short*)(tail + 262144 + 131072);   // 2 MiB (q,k,v,o)

    cast_w<<<dim3(1024), dim3(256), 0, stream>>>(Wq, Wk, Wv, Wo, Wbf);
    xsum_part<<<dim3(4, 32), dim3(256), 0, stream>>>(xf, part);
    xsum_reduce<<<dim3(8), dim3(256), 0, stream>>>(part, xsum);
    qsum_kernel<<<dim3(512), dim3(256), 0, stream>>>(xsum, Wq, bq, Qsum);
    rbias_kernel<<<dim3(4104), dim3(256), 0, stream>>>(Qsum, rel, Rbuf);
    rmax_kernel<<<dim3(32), dim3(256), 0, stream>>>(Rbuf, Mbuf);
    qkv_fused<<<dim3(8, 64), dim3(256), 0, stream>>>(xf, Wbf, bq, bk, bv, Qb, Kb, VbT);
    attn_kernel<<<dim3(16, 32), dim3(256), 0, stream>>>(Qb, Kb, VbT, Rbuf, Mbuf);
    out_proj<<<dim3(8, 64), dim3(256), 0, stream>>>(Qb, Wbf + 3 * 262144, bo, out);
}

// Round 16
// 171.698 us; speedup vs baseline: 1.7209x; 1.1537x over previous
//
#include <hip/hip_runtime.h>
#include <stdint.h>

typedef __bf16  bf16x8 __attribute__((ext_vector_type(8)));
typedef float   f32x4  __attribute__((ext_vector_type(4)));

#define MFMA16(a, b, c) __builtin_amdgcn_mfma_f32_16x16x32_bf16((a), (b), (c), 0, 0, 0)

__device__ __forceinline__ float bf2f(unsigned short u) {
    union { unsigned u; float f; } v; v.u = ((unsigned)u) << 16; return v.f;
}
__device__ __forceinline__ unsigned short f2bf(float f) {
    union { float f; unsigned u; } v; v.f = f;
    unsigned r = v.u + 0x7fffu + ((v.u >> 16) & 1u);
    return (unsigned short)(r >> 16);
}

// B=4, T=1024, D=512, H=8, DH=64, MAX_REL=256. Inputs fp32 dict-order; OUTPUT FP32.
// R16: attn back to tile-64 (R13 geometry; tile-128 measured -15us worse in R15)
// + double-buffered Ks/Vt -> one barrier per K-iter instead of two.

// ---------- 0. cast 4 weights fp32 -> bf16 (order: q,k,v,o) ----------
__global__ __launch_bounds__(256) void cast_w(const float* __restrict__ Wq,
                                              const float* __restrict__ Wk,
                                              const float* __restrict__ Wv,
                                              const float* __restrict__ Wo,
                                              unsigned short* __restrict__ Wbf) {
    int idx = blockIdx.x * 256 + threadIdx.x;      // 1024 x 256 chunks of 4
    int which = idx >> 16, off = (idx & 65535) << 2;
    const float* src = which == 0 ? Wq : which == 1 ? Wk : which == 2 ? Wv : Wo;
    f32x4 v = *(const f32x4*)(src + off);
    ushort4 r;
    r.x = f2bf(v[0]); r.y = f2bf(v[1]); r.z = f2bf(v[2]); r.w = f2bf(v[3]);
    *(ushort4*)(Wbf + (size_t)which * 262144 + off) = r;
}

// ---------- 1a. xsum partials ----------
__global__ __launch_bounds__(256) void xsum_part(const float* __restrict__ x,
                                                 float* __restrict__ part) {
    int b = blockIdx.x, chunk = blockIdx.y, k = threadIdx.x;   // (4,32) x 256
    const float* p = x + (size_t)b * 1024 * 512 + (size_t)chunk * 32 * 512;
    float s0 = 0.f, s1 = 0.f;
    for (int t = 0; t < 32; ++t) {
        s0 += p[t * 512 + k];
        s1 += p[t * 512 + k + 256];
    }
    part[(size_t)(b * 32 + chunk) * 512 + k]       = s0;
    part[(size_t)(b * 32 + chunk) * 512 + k + 256] = s1;
}

// ---------- 1b. xsum reduce ----------
__global__ __launch_bounds__(256) void xsum_reduce(const float* __restrict__ part,
                                                   float* __restrict__ xsum) {
    int idx = blockIdx.x * 256 + threadIdx.x;      // 8 x 256
    int b = idx >> 9, k = idx & 511;
    float s = 0.f;
    for (int c = 0; c < 32; ++c) s += part[(size_t)(b * 32 + c) * 512 + k];
    xsum[idx] = s;
}

// ---------- 2. Qsum (wave per output; 512 blocks) ----------
__global__ __launch_bounds__(256) void qsum_kernel(const float* __restrict__ xsum,
                                                   const float* __restrict__ Wq,
                                                   const float* __restrict__ bq,
                                                   float* __restrict__ Qsum) {
    int idx = blockIdx.x * 4 + (threadIdx.x >> 6);
    int lane = threadIdx.x & 63;
    int b = idx >> 9, n = idx & 511;
    const float* xs = xsum + b * 512;
    const float* w = Wq + (size_t)n * 512;
    float s = 0.f;
    for (int j = lane; j < 512; j += 64) s += xs[j] * w[j];
    for (int off = 32; off; off >>= 1) s += __shfl_xor(s, off, 64);
    if (lane == 0) Qsum[idx] = s + 1024.0f * bq[n];
}

// ---------- 3. R bias (wave per output; 4104 blocks) ----------
__global__ __launch_bounds__(256) void rbias_kernel(const float* __restrict__ Qsum,
                                                    const float* __restrict__ relT,
                                                    float* __restrict__ R) {
    int idx = blockIdx.x * 4 + (threadIdx.x >> 6);
    if (idx >= 4 * 8 * 513) return;
    int lane = threadIdx.x & 63;
    int delta = idx % 513, bh = idx / 513;
    int b = bh >> 3, h = bh & 7;
    float s = Qsum[b * 512 + h * 64 + lane] * relT[(size_t)delta * 64 + lane];
    for (int off = 32; off; off >>= 1) s += __shfl_xor(s, off, 64);
    if (lane == 0) R[idx] = 0.125f * s;
}

// ---------- 3b. M[bh][t] = exact max of R over clipped delta window ----------
__global__ __launch_bounds__(256) void rmax_kernel(const float* __restrict__ R,
                                                   float* __restrict__ M) {
    __shared__ float L[2][513];
    __shared__ float L8[513];
    int bh = blockIdx.x, tid = threadIdx.x;
    for (int i = tid; i < 513; i += 256) L[0][i] = R[bh * 513 + i];
    __syncthreads();
    int cur = 0;
    for (int k = 1; k <= 9; ++k) {
        int half = 1 << (k - 1), nxt = cur ^ 1;
        for (int i = tid; i < 513; i += 256) {
            int j = i + half; if (j > 512) j = 512;
            L[nxt][i] = fmaxf(L[cur][i], L[cur][j]);
        }
        __syncthreads();
        if (k == 8) {
            for (int i = tid; i < 513; i += 256) L8[i] = L[nxt][i];
            __syncthreads();
        }
        cur = nxt;
    }
    for (int t = tid; t < 1024; t += 256) {
        int lo = 256 - (t < 256 ? t : 256);
        int hi = 256 + ((1023 - t) < 256 ? (1023 - t) : 256);
        int len = hi - lo + 1;
        float m = (len >= 512) ? fmaxf(L[cur][lo], L[cur][hi - 511])
                               : fmaxf(L8[lo], L8[hi - 255]);
        M[bh * 1024 + t] = m;
    }
}

// ---------- fp32 64x64 tile (ld=512) -> bf16 LDS [64][72] ----------
__device__ __forceinline__ void stage_f32(const float* __restrict__ src, int row0, int k0,
                                          unsigned short (*dst)[72], int tid) {
    for (int c = tid; c < 1024; c += 256) {
        int row = c >> 4, kc = (c & 15) << 2;
        f32x4 v = *(const f32x4*)(src + (size_t)(row0 + row) * 512 + k0 + kc);
        ushort4 r;
        r.x = f2bf(v[0]); r.y = f2bf(v[1]); r.z = f2bf(v[2]); r.w = f2bf(v[3]);
        *(ushort4*)(&dst[row][kc]) = r;
    }
}

// ---------- 4. FUSED QKV projection (MFMA). Q,K -> (B,H,T,DH); V -> (B,H,DH,T) ----------
__global__ __launch_bounds__(256) void qkv_fused(
    const float* __restrict__ x, const unsigned short* __restrict__ Wbf,
    const float* __restrict__ bq, const float* __restrict__ bk, const float* __restrict__ bv,
    unsigned short* __restrict__ Qb, unsigned short* __restrict__ Kb,
    unsigned short* __restrict__ VbT) {
    const int m0 = blockIdx.y * 64;
    const int n0 = blockIdx.x * 64;

    __shared__ __align__(16) unsigned short As[64][72];
    __shared__ __align__(16) unsigned short Ws3[3][64][72];

    int tid = threadIdx.x;
    int wave = tid >> 6, lane = tid & 63, quad = lane >> 4, l16 = lane & 15;
    int arow = wave * 16 + l16;

    f32x4 acc[3][4] = {};

    for (int k0 = 0; k0 < 512; k0 += 64) {
        stage_f32(x, m0, k0, As, tid);
        for (int w = 0; w < 3; ++w) {
            const unsigned short* Wp = Wbf + (size_t)w * 262144;
            for (int c = tid; c < 512; c += 256) {
                int row = c >> 3, kc = (c & 7) << 3;
                *(uint4*)(&Ws3[w][row][kc]) =
                    *(const uint4*)(Wp + (size_t)(n0 + row) * 512 + k0 + kc);
            }
        }
        __syncthreads();
        for (int kk = 0; kk < 2; ++kk) {
            bf16x8 af = *(const bf16x8*)(&As[arow][kk * 32 + quad * 8]);
            for (int w = 0; w < 3; ++w) {
                for (int nt = 0; nt < 4; ++nt) {
                    bf16x8 bfv = *(const bf16x8*)(&Ws3[w][nt * 16 + l16][kk * 32 + quad * 8]);
                    acc[w][nt] = MFMA16(af, bfv, acc[w][nt]);
                }
            }
        }
        __syncthreads();
    }

    for (int w = 0; w < 2; ++w) {
        unsigned short* Out = (w == 0) ? Qb : Kb;
        const float* bias = (w == 0) ? bq : bk;
        for (int nt = 0; nt < 4; ++nt) {
            int col = n0 + nt * 16 + l16;
            int h = col >> 6, d = col & 63;
            float bv_ = bias[col];
            for (int reg = 0; reg < 4; ++reg) {
                int row = m0 + wave * 16 + quad * 4 + reg;     // = b*1024 + t
                int b = row >> 10, t = row & 1023;
                Out[(((size_t)(b * 8 + h) * 1024 + t) << 6) + d] = f2bf(acc[w][nt][reg] + bv_);
            }
        }
    }
    __syncthreads();
    for (int nt = 0; nt < 4; ++nt) {
        int dl = nt * 16 + l16;
        float bv_ = bv[n0 + dl];
        for (int reg = 0; reg < 4; ++reg)
            As[dl][wave * 16 + quad * 4 + reg] = f2bf(acc[2][nt][reg] + bv_);
    }
    __syncthreads();
    const int h = n0 >> 6, b = m0 >> 10, tg = m0 & 1023;
    for (int c = tid; c < 512; c += 256) {
        int dl = c >> 3, seg = (c & 7) << 3;
        *(uint4*)(VbT + (((size_t)((b * 8 + h) * 64 + dl)) << 10) + tg + seg) =
            *(const uint4*)(&As[dl][seg]);
    }
}

// ---------- 5. MFMA flash attention, tile-64, double-buffered Ks/Vt (1 barrier/iter) ----------
__global__ __launch_bounds__(256) void attn_kernel(
    unsigned short* __restrict__ Qb,
    const unsigned short* __restrict__ Kb, const unsigned short* __restrict__ VbT,
    const float* __restrict__ R, const float* __restrict__ M) {
    const int bh = blockIdx.y;
    const int t0 = blockIdx.x * 64;
    __shared__ __align__(16) unsigned short Ks[2][64][72];
    __shared__ __align__(16) unsigned short Vt[2][64][72];
    __shared__ __align__(16) unsigned short Ps[64][72];
    __shared__ float Rs[513];

    int tid = threadIdx.x, wave = tid >> 6, lane = tid & 63, quad = lane >> 4, l16 = lane & 15;

    for (int i = tid; i < 513; i += 256) Rs[i] = R[bh * 513 + i];

    unsigned short* Qp = Qb + ((size_t)bh * 1024 + t0) * 64;
    int arow = wave * 16 + l16;
    bf16x8 qf0 = *(const bf16x8*)(Qp + arow * 64 + quad * 8);
    bf16x8 qf1 = *(const bf16x8*)(Qp + arow * 64 + 32 + quad * 8);

    float mrow[4];
    for (int reg = 0; reg < 4; ++reg)
        mrow[reg] = M[bh * 1024 + t0 + wave * 16 + quad * 4 + reg];

    const unsigned short* Kp  = Kb  + (size_t)bh * 65536;
    const unsigned short* Vtp = VbT + (size_t)bh * 65536;

    // staging coords: two uint4 chunks per thread per array (64x64 tile)
    int c0 = tid, c1 = tid + 256;
    int r0 = c0 >> 3, kc0 = (c0 & 7) << 3;
    int r1 = c1 >> 3, kc1 = (c1 & 7) << 3;

    uint4 kreg0 = *(const uint4*)(Kp + (size_t)r0 * 64 + kc0);
    uint4 kreg1 = *(const uint4*)(Kp + (size_t)r1 * 64 + kc1);
    uint4 vreg0 = *(const uint4*)(Vtp + ((size_t)r0 << 10) + kc0);
    uint4 vreg1 = *(const uint4*)(Vtp + ((size_t)r1 << 10) + kc1);

    f32x4 acco[4] = {};
    float lsum[4] = {0.f, 0.f, 0.f, 0.f};
    int p = 0;

    for (int s0 = 0; s0 < 1024; s0 += 64) {
        // write current tile into buffer p (other buffer may still be read by slow waves)
        *(uint4*)(&Ks[p][r0][kc0]) = kreg0;
        *(uint4*)(&Ks[p][r1][kc1]) = kreg1;
        *(uint4*)(&Vt[p][r0][kc0]) = vreg0;
        *(uint4*)(&Vt[p][r1][kc1]) = vreg1;
        int sn = s0 + 64;
        if (sn < 1024) {   // prefetch next tile (latency hidden behind compute)
            kreg0 = *(const uint4*)(Kp + (size_t)(sn + r0) * 64 + kc0);
            kreg1 = *(const uint4*)(Kp + (size_t)(sn + r1) * 64 + kc1);
            vreg0 = *(const uint4*)(Vtp + ((size_t)r0 << 10) + sn + kc0);
            vreg1 = *(const uint4*)(Vtp + ((size_t)r1 << 10) + sn + kc1);
        }
        __syncthreads();   // buffer p staged; sole barrier this iteration

        // S = Q K^T
        f32x4 accs[4] = {};
        for (int nt = 0; nt < 4; ++nt) {
            bf16x8 kf0 = *(const bf16x8*)(&Ks[p][nt * 16 + l16][quad * 8]);
            accs[nt] = MFMA16(qf0, kf0, accs[nt]);
            bf16x8 kf1 = *(const bf16x8*)(&Ks[p][nt * 16 + l16][32 + quad * 8]);
            accs[nt] = MFMA16(qf1, kf1, accs[nt]);
        }

        // static-max softmax; per-lane l accumulation
        for (int reg = 0; reg < 4; ++reg) {
            int tt = t0 + wave * 16 + quad * 4 + reg;
            for (int nt = 0; nt < 4; ++nt) {
                int ss = s0 + nt * 16 + l16;
                int dlt = ss - tt;
                dlt = dlt > 256 ? 256 : (dlt < -256 ? -256 : dlt);
                float v = accs[nt][reg] * 0.125f + Rs[dlt + 256];
                float p_ = __expf(v - mrow[reg]);
                lsum[reg] += p_;
                Ps[wave * 16 + quad * 4 + reg][nt * 16 + l16] = f2bf(p_);
            }
        }
        // Ps rows wave-private: program order suffices before PV

        for (int kk = 0; kk < 2; ++kk) {
            bf16x8 pf = *(const bf16x8*)(&Ps[wave * 16 + l16][kk * 32 + quad * 8]);
            for (int nt = 0; nt < 4; ++nt) {
                bf16x8 vf = *(const bf16x8*)(&Vt[p][nt * 16 + l16][kk * 32 + quad * 8]);
                acco[nt] = MFMA16(pf, vf, acco[nt]);
            }
        }
        p ^= 1;
    }

    for (int reg = 0; reg < 4; ++reg)
        for (int off = 1; off < 16; off <<= 1) lsum[reg] += __shfl_xor(lsum[reg], off, 64);

    for (int nt = 0; nt < 4; ++nt) {
        for (int reg = 0; reg < 4; ++reg) {
            int tt = t0 + wave * 16 + quad * 4 + reg;
            int d = nt * 16 + l16;
            Qb[((size_t)bh * 1024 + tt) * 64 + d] = f2bf(acco[nt][reg] / lsum[reg]);
        }
    }
}

// ---------- 6. output projection (MFMA, bf16 Wo): out = AO @ Wo^T + bo, fp32 ----------
__global__ __launch_bounds__(256) void out_proj(
    const unsigned short* __restrict__ AObf, const unsigned short* __restrict__ Wobf,
    const float* __restrict__ bo, float* __restrict__ out) {
    const int m0 = blockIdx.y * 64;
    const int n0 = blockIdx.x * 64;
    const int b = m0 >> 10, tt0 = m0 & 1023;
    __shared__ __align__(16) unsigned short As[64][72];
    __shared__ __align__(16) unsigned short Bs[64][72];
    int tid = threadIdx.x, wave = tid >> 6, lane = tid & 63, quad = lane >> 4, l16 = lane & 15;
    int arow = wave * 16 + l16;
    f32x4 acc[4] = {};
    for (int k0 = 0; k0 < 512; k0 += 64) {
        const int h = k0 >> 6;
        for (int c = tid; c < 512; c += 256) {
            int row = c >> 3, kc = (c & 7) << 3;
            *(uint4*)(&As[row][kc]) =
                *(const uint4*)(AObf + (((size_t)(b * 8 + h) * 1024 + tt0 + row) << 6) + kc);
            *(uint4*)(&Bs[row][kc]) =
                *(const uint4*)(Wobf + (size_t)(n0 + row) * 512 + k0 + kc);
        }
        __syncthreads();
        for (int kk = 0; kk < 2; ++kk) {
            bf16x8 af = *(const bf16x8*)(&As[arow][kk * 32 + quad * 8]);
            for (int nt = 0; nt < 4; ++nt) {
                bf16x8 bfv = *(const bf16x8*)(&Bs[nt * 16 + l16][kk * 32 + quad * 8]);
                acc[nt] = MFMA16(af, bfv, acc[nt]);
            }
        }
        __syncthreads();
    }
    for (int nt = 0; nt < 4; ++nt) {
        int col = n0 + nt * 16 + l16;
        float bv_ = bo[col];
        for (int reg = 0; reg < 4; ++reg) {
            int row = m0 + wave * 16 + quad * 4 + reg;
            out[(size_t)row * 512 + col] = acc[nt][reg] + bv_;
        }
    }
}

extern "C" void kernel_launch(void* const* d_in, const int* in_sizes, int n_in,
                              void* d_out, int out_size, void* d_ws, size_t ws_size,
                              hipStream_t stream) {
    const void* x = nullptr; const void* Ws[4] = {}; const void* bs[4] = {};
    const void* relT = nullptr;
    int wi = 0, bi = 0, idx_x = -1;
    for (int i = 0; i < n_in; ++i) {
        long s = in_sizes[i];
        if ((s == 2097152 || s == 8388608) && !x) { x = d_in[i]; idx_x = i; }
        else if ((s == 262144 || s == 1048576) && wi < 4) Ws[wi++] = d_in[i];
        else if ((s == 512 || s == 2048) && bi < 4) bs[bi++] = d_in[i];
        else if ((s == 32832 || s == 131328) && !relT) relT = d_in[i];
    }
    const float *Wq, *Wk, *Wv, *Wo, *bq, *bk, *bv, *bo;
    if (x && wi == 4 && bi == 4 && relT) {
        bool sorted_order = (idx_x != 0);    // measured: dict order (idx_x==0)
        if (sorted_order) {
            Wq = (const float*)Ws[2]; Wk = (const float*)Ws[0];
            Wv = (const float*)Ws[3]; Wo = (const float*)Ws[1];
            bq = (const float*)bs[2]; bk = (const float*)bs[0];
            bv = (const float*)bs[3]; bo = (const float*)bs[1];
        } else {
            Wq = (const float*)Ws[0]; Wk = (const float*)Ws[1];
            Wv = (const float*)Ws[2]; Wo = (const float*)Ws[3];
            bq = (const float*)bs[0]; bk = (const float*)bs[1];
            bv = (const float*)bs[2]; bo = (const float*)bs[3];
        }
    } else {
        x = d_in[0];
        Wq = (const float*)d_in[2]; bq = (const float*)d_in[3];
        Wk = (const float*)d_in[4]; bk = (const float*)d_in[5];
        Wv = (const float*)d_in[6]; bv = (const float*)d_in[7];
        Wo = (const float*)d_in[8]; bo = (const float*)d_in[9];
        relT = d_in[10];
    }
    const float* xf  = (const float*)x;
    const float* rel = (const float*)relT;
    float* out = (float*)d_out;

    // ws: hdr 128K | Qb/Kb/VbT 3x4M | part 256K | M 128K | Wbf 2M  = 14.5 MiB
    char* ws = (char*)d_ws;
    float* xsum = (float*)(ws);
    float* Qsum = (float*)(ws + 8192);
    float* Rbuf = (float*)(ws + 16384);
    unsigned short* Qb  = (unsigned short*)(ws + 131072);
    unsigned short* Kb  = (unsigned short*)(ws + 131072 + (4 << 20));
    unsigned short* VbT = (unsigned short*)(ws + 131072 + (8 << 20));
    char* tail = ws + 131072 + (12 << 20);
    float* part = (float*)(tail);                        // 256 KB
    float* Mbuf = (float*)(tail + 262144);               // 128 KB
    unsigned short* Wbf = (unsigned short*)(tail + 262144 + 131072);   // 2 MiB (q,k,v,o)

    cast_w<<<dim3(1024), dim3(256), 0, stream>>>(Wq, Wk, Wv, Wo, Wbf);
    xsum_part<<<dim3(4, 32), dim3(256), 0, stream>>>(xf, part);
    xsum_reduce<<<dim3(8), dim3(256), 0, stream>>>(part, xsum);
    qsum_kernel<<<dim3(512), dim3(256), 0, stream>>>(xsum, Wq, bq, Qsum);
    rbias_kernel<<<dim3(4104), dim3(256), 0, stream>>>(Qsum, rel, Rbuf);
    rmax_kernel<<<dim3(32), dim3(256), 0, stream>>>(Rbuf, Mbuf);
    qkv_fused<<<dim3(8, 64), dim3(256), 0, stream>>>(xf, Wbf, bq, bk, bv, Qb, Kb, VbT);
    attn_kernel<<<dim3(16, 32), dim3(256), 0, stream>>>(Qb, Kb, VbT, Rbuf, Mbuf);
    out_proj<<<dim3(8, 64), dim3(256), 0, stream>>>(Qb, Wbf + 3 * 262144, bo, out);
}

// Round 17
// 166.313 us; speedup vs baseline: 1.7766x; 1.0324x over previous
//
#include <hip/hip_runtime.h>
#include <stdint.h>

typedef __bf16  bf16x8 __attribute__((ext_vector_type(8)));
typedef float   f32x4  __attribute__((ext_vector_type(4)));

#define MFMA16(a, b, c) __builtin_amdgcn_mfma_f32_16x16x32_bf16((a), (b), (c), 0, 0, 0)

__device__ __forceinline__ float bf2f(unsigned short u) {
    union { unsigned u; float f; } v; v.u = ((unsigned)u) << 16; return v.f;
}
__device__ __forceinline__ unsigned short f2bf(float f) {
    union { float f; unsigned u; } v; v.f = f;
    unsigned r = v.u + 0x7fffu + ((v.u >> 16) & 1u);
    return (unsigned short)(r >> 16);
}

// B=4, T=1024, D=512, H=8, DH=64, MAX_REL=256. Inputs fp32 dict-order; OUTPUT FP32.
// R17: qkv gets the attn treatment — x pre-cast to bf16 (once), double-buffered
// LDS + register prefetch, one barrier per K-iteration.

// ---------- 0. cast weights AND x fp32 -> bf16 ----------
__global__ __launch_bounds__(256) void cast_wx(const float* __restrict__ Wq,
                                               const float* __restrict__ Wk,
                                               const float* __restrict__ Wv,
                                               const float* __restrict__ Wo,
                                               const float* __restrict__ x,
                                               unsigned short* __restrict__ Wbf,
                                               unsigned short* __restrict__ xbf) {
    int bid = blockIdx.x;
    if (bid < 1024) {             // weights: 262144 chunks of 4
        int idx = bid * 256 + threadIdx.x;
        int which = idx >> 16, off = (idx & 65535) << 2;
        const float* src = which == 0 ? Wq : which == 1 ? Wk : which == 2 ? Wv : Wo;
        f32x4 v = *(const f32x4*)(src + off);
        ushort4 r;
        r.x = f2bf(v[0]); r.y = f2bf(v[1]); r.z = f2bf(v[2]); r.w = f2bf(v[3]);
        *(ushort4*)(Wbf + (size_t)which * 262144 + off) = r;
    } else {                      // x: 524288 chunks of 4
        int cidx = (bid - 1024) * 256 + threadIdx.x;
        size_t off = (size_t)cidx << 2;
        f32x4 v = *(const f32x4*)(x + off);
        ushort4 r;
        r.x = f2bf(v[0]); r.y = f2bf(v[1]); r.z = f2bf(v[2]); r.w = f2bf(v[3]);
        *(ushort4*)(xbf + off) = r;
    }
}

// ---------- 1a. xsum partials ----------
__global__ __launch_bounds__(256) void xsum_part(const float* __restrict__ x,
                                                 float* __restrict__ part) {
    int b = blockIdx.x, chunk = blockIdx.y, k = threadIdx.x;   // (4,32) x 256
    const float* p = x + (size_t)b * 1024 * 512 + (size_t)chunk * 32 * 512;
    float s0 = 0.f, s1 = 0.f;
    for (int t = 0; t < 32; ++t) {
        s0 += p[t * 512 + k];
        s1 += p[t * 512 + k + 256];
    }
    part[(size_t)(b * 32 + chunk) * 512 + k]       = s0;
    part[(size_t)(b * 32 + chunk) * 512 + k + 256] = s1;
}

// ---------- 1b. xsum reduce ----------
__global__ __launch_bounds__(256) void xsum_reduce(const float* __restrict__ part,
                                                   float* __restrict__ xsum) {
    int idx = blockIdx.x * 256 + threadIdx.x;      // 8 x 256
    int b = idx >> 9, k = idx & 511;
    float s = 0.f;
    for (int c = 0; c < 32; ++c) s += part[(size_t)(b * 32 + c) * 512 + k];
    xsum[idx] = s;
}

// ---------- 2. Qsum (wave per output; 512 blocks) ----------
__global__ __launch_bounds__(256) void qsum_kernel(const float* __restrict__ xsum,
                                                   const float* __restrict__ Wq,
                                                   const float* __restrict__ bq,
                                                   float* __restrict__ Qsum) {
    int idx = blockIdx.x * 4 + (threadIdx.x >> 6);
    int lane = threadIdx.x & 63;
    int b = idx >> 9, n = idx & 511;
    const float* xs = xsum + b * 512;
    const float* w = Wq + (size_t)n * 512;
    float s = 0.f;
    for (int j = lane; j < 512; j += 64) s += xs[j] * w[j];
    for (int off = 32; off; off >>= 1) s += __shfl_xor(s, off, 64);
    if (lane == 0) Qsum[idx] = s + 1024.0f * bq[n];
}

// ---------- 3. R bias (wave per output; 4104 blocks) ----------
__global__ __launch_bounds__(256) void rbias_kernel(const float* __restrict__ Qsum,
                                                    const float* __restrict__ relT,
                                                    float* __restrict__ R) {
    int idx = blockIdx.x * 4 + (threadIdx.x >> 6);
    if (idx >= 4 * 8 * 513) return;
    int lane = threadIdx.x & 63;
    int delta = idx % 513, bh = idx / 513;
    int b = bh >> 3, h = bh & 7;
    float s = Qsum[b * 512 + h * 64 + lane] * relT[(size_t)delta * 64 + lane];
    for (int off = 32; off; off >>= 1) s += __shfl_xor(s, off, 64);
    if (lane == 0) R[idx] = 0.125f * s;
}

// ---------- 3b. M[bh][t] = exact max of R over clipped delta window ----------
__global__ __launch_bounds__(256) void rmax_kernel(const float* __restrict__ R,
                                                   float* __restrict__ M) {
    __shared__ float L[2][513];
    __shared__ float L8[513];
    int bh = blockIdx.x, tid = threadIdx.x;
    for (int i = tid; i < 513; i += 256) L[0][i] = R[bh * 513 + i];
    __syncthreads();
    int cur = 0;
    for (int k = 1; k <= 9; ++k) {
        int half = 1 << (k - 1), nxt = cur ^ 1;
        for (int i = tid; i < 513; i += 256) {
            int j = i + half; if (j > 512) j = 512;
            L[nxt][i] = fmaxf(L[cur][i], L[cur][j]);
        }
        __syncthreads();
        if (k == 8) {
            for (int i = tid; i < 513; i += 256) L8[i] = L[nxt][i];
            __syncthreads();
        }
        cur = nxt;
    }
    for (int t = tid; t < 1024; t += 256) {
        int lo = 256 - (t < 256 ? t : 256);
        int hi = 256 + ((1023 - t) < 256 ? (1023 - t) : 256);
        int len = hi - lo + 1;
        float m = (len >= 512) ? fmaxf(L[cur][lo], L[cur][hi - 511])
                               : fmaxf(L8[lo], L8[hi - 255]);
        M[bh * 1024 + t] = m;
    }
}

// ---------- 4. FUSED QKV projection, dbuf + reg prefetch (all-bf16 staging) ----------
// Q,K -> (B,H,T,DH); V -> (B,H,DH,T).
__global__ __launch_bounds__(256) void qkv_fused(
    const unsigned short* __restrict__ xbf, const unsigned short* __restrict__ Wbf,
    const float* __restrict__ bq, const float* __restrict__ bk, const float* __restrict__ bv,
    unsigned short* __restrict__ Qb, unsigned short* __restrict__ Kb,
    unsigned short* __restrict__ VbT) {
    const int m0 = blockIdx.y * 64;
    const int n0 = blockIdx.x * 64;

    __shared__ __align__(16) unsigned short As[2][64][72];
    __shared__ __align__(16) unsigned short Ws3[2][3][64][72];

    int tid = threadIdx.x;
    int wave = tid >> 6, lane = tid & 63, quad = lane >> 4, l16 = lane & 15;
    int arow = wave * 16 + l16;

    // staging coords: 512 uint4 chunks per 64x64 tile -> 2 per thread
    int c0 = tid, c1 = tid + 256;
    int r0 = c0 >> 3, kc0 = (c0 & 7) << 3;
    int r1 = c1 >> 3, kc1 = (c1 & 7) << 3;

    // prefetch k0 = 0
    uint4 xr0 = *(const uint4*)(xbf + (size_t)(m0 + r0) * 512 + kc0);
    uint4 xr1 = *(const uint4*)(xbf + (size_t)(m0 + r1) * 512 + kc1);
    uint4 wr[3][2];
    for (int w = 0; w < 3; ++w) {
        const unsigned short* Wp = Wbf + (size_t)w * 262144;
        wr[w][0] = *(const uint4*)(Wp + (size_t)(n0 + r0) * 512 + kc0);
        wr[w][1] = *(const uint4*)(Wp + (size_t)(n0 + r1) * 512 + kc1);
    }

    f32x4 acc[3][4] = {};
    int p = 0;

    for (int k0 = 0; k0 < 512; k0 += 64) {
        *(uint4*)(&As[p][r0][kc0]) = xr0;
        *(uint4*)(&As[p][r1][kc1]) = xr1;
        for (int w = 0; w < 3; ++w) {
            *(uint4*)(&Ws3[p][w][r0][kc0]) = wr[w][0];
            *(uint4*)(&Ws3[p][w][r1][kc1]) = wr[w][1];
        }
        int kn = k0 + 64;
        if (kn < 512) {   // prefetch next K-tile; latency hidden behind MFMA below
            xr0 = *(const uint4*)(xbf + (size_t)(m0 + r0) * 512 + kn + kc0);
            xr1 = *(const uint4*)(xbf + (size_t)(m0 + r1) * 512 + kn + kc1);
            for (int w = 0; w < 3; ++w) {
                const unsigned short* Wp = Wbf + (size_t)w * 262144;
                wr[w][0] = *(const uint4*)(Wp + (size_t)(n0 + r0) * 512 + kn + kc0);
                wr[w][1] = *(const uint4*)(Wp + (size_t)(n0 + r1) * 512 + kn + kc1);
            }
        }
        __syncthreads();   // buffer p staged; sole barrier this iteration
        for (int kk = 0; kk < 2; ++kk) {
            bf16x8 af = *(const bf16x8*)(&As[p][arow][kk * 32 + quad * 8]);
            for (int w = 0; w < 3; ++w) {
                for (int nt = 0; nt < 4; ++nt) {
                    bf16x8 bfv = *(const bf16x8*)(&Ws3[p][w][nt * 16 + l16][kk * 32 + quad * 8]);
                    acc[w][nt] = MFMA16(af, bfv, acc[w][nt]);
                }
            }
        }
        p ^= 1;
    }

    // Q, K epilogue (C: row = m0+wave*16+quad*4+reg, col = n0+nt*16+l16)
    for (int w = 0; w < 2; ++w) {
        unsigned short* Out = (w == 0) ? Qb : Kb;
        const float* bias = (w == 0) ? bq : bk;
        for (int nt = 0; nt < 4; ++nt) {
            int col = n0 + nt * 16 + l16;
            int h = col >> 6, d = col & 63;
            float bv_ = bias[col];
            for (int reg = 0; reg < 4; ++reg) {
                int row = m0 + wave * 16 + quad * 4 + reg;     // = b*1024 + t
                int b = row >> 10, t = row & 1023;
                Out[(((size_t)(b * 8 + h) * 1024 + t) << 6) + d] = f2bf(acc[w][nt][reg] + bv_);
            }
        }
    }
    // V epilogue: transpose via LDS (reuse As[0]), coalesced write to VbT (B,H,DH,T)
    __syncthreads();
    for (int nt = 0; nt < 4; ++nt) {
        int dl = nt * 16 + l16;
        float bv_ = bv[n0 + dl];
        for (int reg = 0; reg < 4; ++reg)
            As[0][dl][wave * 16 + quad * 4 + reg] = f2bf(acc[2][nt][reg] + bv_);
    }
    __syncthreads();
    const int h = n0 >> 6, b = m0 >> 10, tg = m0 & 1023;
    for (int c = tid; c < 512; c += 256) {
        int dl = c >> 3, seg = (c & 7) << 3;
        *(uint4*)(VbT + (((size_t)((b * 8 + h) * 64 + dl)) << 10) + tg + seg) =
            *(const uint4*)(&As[0][dl][seg]);
    }
}

// ---------- 5. MFMA flash attention, tile-64, dbuf Ks/Vt (1 barrier/iter) ----------
__global__ __launch_bounds__(256) void attn_kernel(
    unsigned short* __restrict__ Qb,
    const unsigned short* __restrict__ Kb, const unsigned short* __restrict__ VbT,
    const float* __restrict__ R, const float* __restrict__ M) {
    const int bh = blockIdx.y;
    const int t0 = blockIdx.x * 64;
    __shared__ __align__(16) unsigned short Ks[2][64][72];
    __shared__ __align__(16) unsigned short Vt[2][64][72];
    __shared__ __align__(16) unsigned short Ps[64][72];
    __shared__ float Rs[513];

    int tid = threadIdx.x, wave = tid >> 6, lane = tid & 63, quad = lane >> 4, l16 = lane & 15;

    for (int i = tid; i < 513; i += 256) Rs[i] = R[bh * 513 + i];

    unsigned short* Qp = Qb + ((size_t)bh * 1024 + t0) * 64;
    int arow = wave * 16 + l16;
    bf16x8 qf0 = *(const bf16x8*)(Qp + arow * 64 + quad * 8);
    bf16x8 qf1 = *(const bf16x8*)(Qp + arow * 64 + 32 + quad * 8);

    float mrow[4];
    for (int reg = 0; reg < 4; ++reg)
        mrow[reg] = M[bh * 1024 + t0 + wave * 16 + quad * 4 + reg];

    const unsigned short* Kp  = Kb  + (size_t)bh * 65536;
    const unsigned short* Vtp = VbT + (size_t)bh * 65536;

    int c0 = tid, c1 = tid + 256;
    int r0 = c0 >> 3, kc0 = (c0 & 7) << 3;
    int r1 = c1 >> 3, kc1 = (c1 & 7) << 3;

    uint4 kreg0 = *(const uint4*)(Kp + (size_t)r0 * 64 + kc0);
    uint4 kreg1 = *(const uint4*)(Kp + (size_t)r1 * 64 + kc1);
    uint4 vreg0 = *(const uint4*)(Vtp + ((size_t)r0 << 10) + kc0);
    uint4 vreg1 = *(const uint4*)(Vtp + ((size_t)r1 << 10) + kc1);

    f32x4 acco[4] = {};
    float lsum[4] = {0.f, 0.f, 0.f, 0.f};
    int p = 0;

    for (int s0 = 0; s0 < 1024; s0 += 64) {
        *(uint4*)(&Ks[p][r0][kc0]) = kreg0;
        *(uint4*)(&Ks[p][r1][kc1]) = kreg1;
        *(uint4*)(&Vt[p][r0][kc0]) = vreg0;
        *(uint4*)(&Vt[p][r1][kc1]) = vreg1;
        int sn = s0 + 64;
        if (sn < 1024) {
            kreg0 = *(const uint4*)(Kp + (size_t)(sn + r0) * 64 + kc0);
            kreg1 = *(const uint4*)(Kp + (size_t)(sn + r1) * 64 + kc1);
            vreg0 = *(const uint4*)(Vtp + ((size_t)r0 << 10) + sn + kc0);
            vreg1 = *(const uint4*)(Vtp + ((size_t)r1 << 10) + sn + kc1);
        }
        __syncthreads();

        f32x4 accs[4] = {};
        for (int nt = 0; nt < 4; ++nt) {
            bf16x8 kf0 = *(const bf16x8*)(&Ks[p][nt * 16 + l16][quad * 8]);
            accs[nt] = MFMA16(qf0, kf0, accs[nt]);
            bf16x8 kf1 = *(const bf16x8*)(&Ks[p][nt * 16 + l16][32 + quad * 8]);
            accs[nt] = MFMA16(qf1, kf1, accs[nt]);
        }

        for (int reg = 0; reg < 4; ++reg) {
            int tt = t0 + wave * 16 + quad * 4 + reg;
            for (int nt = 0; nt < 4; ++nt) {
                int ss = s0 + nt * 16 + l16;
                int dlt = ss - tt;
                dlt = dlt > 256 ? 256 : (dlt < -256 ? -256 : dlt);
                float v = accs[nt][reg] * 0.125f + Rs[dlt + 256];
                float p_ = __expf(v - mrow[reg]);
                lsum[reg] += p_;
                Ps[wave * 16 + quad * 4 + reg][nt * 16 + l16] = f2bf(p_);
            }
        }

        for (int kk = 0; kk < 2; ++kk) {
            bf16x8 pf = *(const bf16x8*)(&Ps[wave * 16 + l16][kk * 32 + quad * 8]);
            for (int nt = 0; nt < 4; ++nt) {
                bf16x8 vf = *(const bf16x8*)(&Vt[p][nt * 16 + l16][kk * 32 + quad * 8]);
                acco[nt] = MFMA16(pf, vf, acco[nt]);
            }
        }
        p ^= 1;
    }

    for (int reg = 0; reg < 4; ++reg)
        for (int off = 1; off < 16; off <<= 1) lsum[reg] += __shfl_xor(lsum[reg], off, 64);

    for (int nt = 0; nt < 4; ++nt) {
        for (int reg = 0; reg < 4; ++reg) {
            int tt = t0 + wave * 16 + quad * 4 + reg;
            int d = nt * 16 + l16;
            Qb[((size_t)bh * 1024 + tt) * 64 + d] = f2bf(acco[nt][reg] / lsum[reg]);
        }
    }
}

// ---------- 6. output projection (MFMA, bf16 Wo): out = AO @ Wo^T + bo, fp32 ----------
__global__ __launch_bounds__(256) void out_proj(
    const unsigned short* __restrict__ AObf, const unsigned short* __restrict__ Wobf,
    const float* __restrict__ bo, float* __restrict__ out) {
    const int m0 = blockIdx.y * 64;
    const int n0 = blockIdx.x * 64;
    const int b = m0 >> 10, tt0 = m0 & 1023;
    __shared__ __align__(16) unsigned short As[64][72];
    __shared__ __align__(16) unsigned short Bs[64][72];
    int tid = threadIdx.x, wave = tid >> 6, lane = tid & 63, quad = lane >> 4, l16 = lane & 15;
    int arow = wave * 16 + l16;
    f32x4 acc[4] = {};
    for (int k0 = 0; k0 < 512; k0 += 64) {
        const int h = k0 >> 6;
        for (int c = tid; c < 512; c += 256) {
            int row = c >> 3, kc = (c & 7) << 3;
            *(uint4*)(&As[row][kc]) =
                *(const uint4*)(AObf + (((size_t)(b * 8 + h) * 1024 + tt0 + row) << 6) + kc);
            *(uint4*)(&Bs[row][kc]) =
                *(const uint4*)(Wobf + (size_t)(n0 + row) * 512 + k0 + kc);
        }
        __syncthreads();
        for (int kk = 0; kk < 2; ++kk) {
            bf16x8 af = *(const bf16x8*)(&As[arow][kk * 32 + quad * 8]);
            for (int nt = 0; nt < 4; ++nt) {
                bf16x8 bfv = *(const bf16x8*)(&Bs[nt * 16 + l16][kk * 32 + quad * 8]);
                acc[nt] = MFMA16(af, bfv, acc[nt]);
            }
        }
        __syncthreads();
    }
    for (int nt = 0; nt < 4; ++nt) {
        int col = n0 + nt * 16 + l16;
        float bv_ = bo[col];
        for (int reg = 0; reg < 4; ++reg) {
            int row = m0 + wave * 16 + quad * 4 + reg;
            out[(size_t)row * 512 + col] = acc[nt][reg] + bv_;
        }
    }
}

extern "C" void kernel_launch(void* const* d_in, const int* in_sizes, int n_in,
                              void* d_out, int out_size, void* d_ws, size_t ws_size,
                              hipStream_t stream) {
    const void* x = nullptr; const void* Ws[4] = {}; const void* bs[4] = {};
    const void* relT = nullptr;
    int wi = 0, bi = 0, idx_x = -1;
    for (int i = 0; i < n_in; ++i) {
        long s = in_sizes[i];
        if ((s == 2097152 || s == 8388608) && !x) { x = d_in[i]; idx_x = i; }
        else if ((s == 262144 || s == 1048576) && wi < 4) Ws[wi++] = d_in[i];
        else if ((s == 512 || s == 2048) && bi < 4) bs[bi++] = d_in[i];
        else if ((s == 32832 || s == 131328) && !relT) relT = d_in[i];
    }
    const float *Wq, *Wk, *Wv, *Wo, *bq, *bk, *bv, *bo;
    if (x && wi == 4 && bi == 4 && relT) {
        bool sorted_order = (idx_x != 0);    // measured: dict order (idx_x==0)
        if (sorted_order) {
            Wq = (const float*)Ws[2]; Wk = (const float*)Ws[0];
            Wv = (const float*)Ws[3]; Wo = (const float*)Ws[1];
            bq = (const float*)bs[2]; bk = (const float*)bs[0];
            bv = (const float*)bs[3]; bo = (const float*)bs[1];
        } else {
            Wq = (const float*)Ws[0]; Wk = (const float*)Ws[1];
            Wv = (const float*)Ws[2]; Wo = (const float*)Ws[3];
            bq = (const float*)bs[0]; bk = (const float*)bs[1];
            bv = (const float*)bs[2]; bo = (const float*)bs[3];
        }
    } else {
        x = d_in[0];
        Wq = (const float*)d_in[2]; bq = (const float*)d_in[3];
        Wk = (const float*)d_in[4]; bk = (const float*)d_in[5];
        Wv = (const float*)d_in[6]; bv = (const float*)d_in[7];
        Wo = (const float*)d_in[8]; bo = (const float*)d_in[9];
        relT = d_in[10];
    }
    const float* xf  = (const float*)x;
    const float* rel = (const float*)relT;
    float* out = (float*)d_out;

    // ws: hdr 128K | Qb/Kb/VbT 3x4M | part 256K | M 128K | Wbf 2M | xbf 4M = 18.5 MiB
    char* ws = (char*)d_ws;
    float* xsum = (float*)(ws);
    float* Qsum = (float*)(ws + 8192);
    float* Rbuf = (float*)(ws + 16384);
    unsigned short* Qb  = (unsigned short*)(ws + 131072);
    unsigned short* Kb  = (unsigned short*)(ws + 131072 + (4 << 20));
    unsigned short* VbT = (unsigned short*)(ws + 131072 + (8 << 20));
    char* tail = ws + 131072 + (12 << 20);
    float* part = (float*)(tail);                        // 256 KB
    float* Mbuf = (float*)(tail + 262144);               // 128 KB
    unsigned short* Wbf = (unsigned short*)(tail + 262144 + 131072);          // 2 MiB
    unsigned short* xbf = (unsigned short*)(tail + 262144 + 131072 + (2 << 20)); // 4 MiB

    cast_wx<<<dim3(3072), dim3(256), 0, stream>>>(Wq, Wk, Wv, Wo, xf, Wbf, xbf);
    xsum_part<<<dim3(4, 32), dim3(256), 0, stream>>>(xf, part);
    xsum_reduce<<<dim3(8), dim3(256), 0, stream>>>(part, xsum);
    qsum_kernel<<<dim3(512), dim3(256), 0, stream>>>(xsum, Wq, bq, Qsum);
    rbias_kernel<<<dim3(4104), dim3(256), 0, stream>>>(Qsum, rel, Rbuf);
    rmax_kernel<<<dim3(32), dim3(256), 0, stream>>>(Rbuf, Mbuf);
    qkv_fused<<<dim3(8, 64), dim3(256), 0, stream>>>(xbf, Wbf, bq, bk, bv, Qb, Kb, VbT);
    attn_kernel<<<dim3(16, 32), dim3(256), 0, stream>>>(Qb, Kb, VbT, Rbuf, Mbuf);
    out_proj<<<dim3(8, 64), dim3(256), 0, stream>>>(Qb, Wbf + 3 * 262144, bo, out);
}